// Round 10
// baseline (256.697 us; speedup 1.0000x reference)
//
#include <hip/hip_runtime.h>
#include <math.h>

// v9: ILP-for-latency. Evidence: MfmaUtil 4.6% == static-count MFMA share of
// wall (5%) -> static counts are right, VALUBusy 75% is a formula artifact,
// kernel is ~80% latency/sync-stalled. Fix: 32 points per block as TWO
// independent 16-point sets (pp=0,1), every stage and the DPP-GJ solve
// processing both sets with interleaved chains. Barriers per point halved.
// Grid 512 (2 blocks/CU, 47KB LDS). vreg made transient to hold VGPR < 256.

typedef _Float16 f16;
typedef _Float16 f16x2 __attribute__((ext_vector_type(2)));
typedef _Float16 f16x4 __attribute__((ext_vector_type(4)));
typedef _Float16 f16x8 __attribute__((ext_vector_type(8)));
typedef __fp16 h16x2 __attribute__((ext_vector_type(2)));
typedef float f32x2 __attribute__((ext_vector_type(2)));
typedef float f32x4 __attribute__((ext_vector_type(4)));
typedef float f32x16 __attribute__((ext_vector_type(16)));

#define SAG_P 392   // f16 point stride; row stride 24, aug col at 16
#define SZ_P  36    // f32
#define SH_P  72    // f16
#define SW_P  20    // f32
#define SWP_C 20    // f32 stride of sWp per (wave,point)
#define NPP   2     // point-sets per block (32 points total)

__device__ __forceinline__ float fastTanh(float x) {
    float e = exp2f(x * 2.885390081777927f);
    return 1.0f - 2.0f * __builtin_amdgcn_rcpf(1.0f + e);
}

__device__ __forceinline__ f16x2 pk2(float a, float b) {
    h16x2 p = __builtin_amdgcn_cvt_pkrtz(a, b);
    return __builtin_bit_cast(f16x2, p);
}

typedef union { f16x4 v4; f16x2 v2[2]; } u16x4;
typedef union { f16x8 v8; f16x2 v2[4]; int i32[4]; } u16x8;

// broadcast lane K of each 16-lane row via DPP row_newbcast (VALU, no DS)
template<int K>
__device__ __forceinline__ float bcf(float x) {
    int v = __builtin_amdgcn_mov_dpp(__builtin_bit_cast(int, x),
                                     0x150 | K, 0xf, 0xf, false);
    return __builtin_bit_cast(float, v);
}

// Two interleaved Gauss-Jordan eliminations (independent chains fill stalls).
template<int K>
__device__ __forceinline__ void fe_all2(float (&R0)[17], float (&R1)[17],
                                        const int i16, float &inv0, float &inv1) {
    if constexpr (K < 16) {
        float p0 = bcf<K>(R0[K]);
        float p1 = bcf<K>(R1[K]);
        float i0 = __builtin_amdgcn_rcpf(p0);
        float i1 = __builtin_amdgcn_rcpf(p1);
        if (i16 == K) { inv0 = i0; inv1 = i1; }
        float f0 = (i16 == K) ? 0.0f : R0[K] * i0;
        float f1 = (i16 == K) ? 0.0f : R1[K] * i1;
        #pragma unroll
        for (int j = K + 1; j <= 16; ++j) {
            float q0 = bcf<K>(R0[j]);
            float q1 = bcf<K>(R1[j]);
            R0[j] -= f0 * q0;
            R1[j] -= f1 * q1;
        }
        fe_all2<K + 1>(R0, R1, i16, inv0, inv1);
    }
}

__global__ __launch_bounds__(256, 1)
void geo_kernel(const float* __restrict__ zin, const float* __restrict__ tg,
                const float* __restrict__ W1g, const float* __restrict__ b1g,
                const float* __restrict__ W2g, const float* __restrict__ b2g,
                const int* __restrict__ nsg, float* __restrict__ outg, int B)
{
    __shared__ __align__(16) f16   sAG[NPP][16 * SAG_P];
    __shared__ __align__(16) f16   sHT[NPP][16 * SH_P];
    __shared__ __align__(16) float sZI[NPP][16 * SZ_P];
    __shared__ __align__(16) float sKV[NPP][16 * SW_P];
    __shared__ __align__(16) float sWp[NPP][4 * 16 * SWP_C];

    const int tid = threadIdx.x;
    const int w = tid >> 6;
    const int l = tid & 63;
    const int i16 = l & 15, q4 = l >> 4, h2 = l >> 5, sc = q4 & 1;

    // ---------------- hoisted weight fragments (quarter per wave) ----------
    f16x8 w2a[4][2];   // A-stage A-op: W2^T[e=i16+16(4w+t)][k=8q4+j+32ch]
    #pragma unroll
    for (int t = 0; t < 4; ++t)
        #pragma unroll
        for (int ch = 0; ch < 2; ++ch)
            #pragma unroll
            for (int j = 0; j < 8; ++j)
                w2a[t][ch][j] = (f16)W2g[(8*q4 + j + 32*ch)*256 + i16 + 16*(4*w + t)];

    f16x8 w2r[8];      // r-stage A-op: W2[n=i16+16w][e=8q4+j+32ch]
    #pragma unroll
    for (int ch = 0; ch < 8; ++ch)
        #pragma unroll
        for (int j = 0; j < 8; ++j)
            w2r[ch][j] = (f16)W2g[(i16 + 16*w)*256 + 8*q4 + j + 32*ch];

    f16x8 w1h;         // H-stage A-op: W1^T[n=i16+16w][x=8q4+j], zero-pad k>=16
    #pragma unroll
    for (int j = 0; j < 8; ++j) {
        int k = 8*q4 + j;
        w1h[j] = (k < 16) ? (f16)W1g[k*64 + i16 + 16*w] : (f16)0.0f;
    }

    f16x8 w1q[2];      // q-stage A-op: W1[i=i16][n=8q4+j+32ch]
    #pragma unroll
    for (int ch = 0; ch < 2; ++ch)
        #pragma unroll
        for (int j = 0; j < 8; ++j)
            w1q[ch][j] = (f16)W1g[i16*64 + 8*q4 + j + 32*ch];

    float b2v[4][4];
    #pragma unroll
    for (int t = 0; t < 4; ++t)
        #pragma unroll
        for (int reg = 0; reg < 4; ++reg)
            b2v[t][reg] = b2g[16*(4*w + t) + 4*q4 + reg];
    float b1v[4];
    #pragma unroll
    for (int reg = 0; reg < 4; ++reg) b1v[reg] = b1g[16*w + 4*q4 + reg];

    // ---------------- RK4 state: thread owns point (pp, tid>>4) ----------
    const int pb = blockIdx.x * 32;
    const int p_cmb = tid >> 4;            // == 4w + q4
    const int g16 = tid & 15;
    f32x2 zc[NPP], ar[NPP];
    #pragma unroll
    for (int pp = 0; pp < NPP; ++pp) {
        int pg = pb + 16*pp + p_cmb;
        if (pg >= B) pg = B - 1;
        zc[pp] = *(const f32x2*)&zin[pg*32 + 2*g16];
        *(f32x2*)&sZI[pp][p_cmb*SZ_P + 2*g16] = zc[pp];
    }
    __syncthreads();

    const float tv = tg[0];
    const int nst = nsg[0];
    const float dt = tv / (float)nst;

    const int xmask = (q4 >= 2) ? 0 : -1;

    float dreg[NPP][4];

    #pragma unroll 1
    for (int st = 0; st < nst; ++st) {
        #pragma unroll 1
        for (int s = 0; s < 4; ++s) {
            // ======== H (both sets): lane point i16, n=16w+4q4+reg ========
            #pragma unroll
            for (int pp = 0; pp < NPP; ++pp) {
                u16x8 xf;
                {
                    f32x4 xa = *(const f32x4*)&sZI[pp][i16*SZ_P + 8*sc];
                    f32x4 xb = *(const f32x4*)&sZI[pp][i16*SZ_P + 8*sc + 4];
                    xf.v2[0] = pk2(xa[0], xa[1]);
                    xf.v2[1] = pk2(xa[2], xa[3]);
                    xf.v2[2] = pk2(xb[0], xb[1]);
                    xf.v2[3] = pk2(xb[2], xb[3]);
                    #pragma unroll
                    for (int jp = 0; jp < 4; ++jp) xf.i32[jp] &= xmask;
                }
                f32x4 hc = {0.f, 0.f, 0.f, 0.f};
                hc = __builtin_amdgcn_mfma_f32_16x16x32_f16(w1h, xf.v8, hc, 0, 0, 0);
                float hv[4];
                #pragma unroll
                for (int reg = 0; reg < 4; ++reg) {
                    hv[reg] = fastTanh(hc[reg] + b1v[reg]);
                    dreg[pp][reg] = hv[reg]*hv[reg] - 1.0f;
                }
                u16x4 hv4;
                hv4.v2[0] = pk2(hv[0], hv[1]);
                hv4.v2[1] = pk2(hv[2], hv[3]);
                *(f16x4*)&sHT[pp][i16*SH_P + 16*w + 4*q4] = hv4.v4;
            }
            __syncthreads();   // B1: h ready
            // ======== A (both sets) + w partials ========
            #pragma unroll
            for (int pp = 0; pp < NPP; ++pp) {
                f16x8 hf0 = *(const f16x8*)&sHT[pp][i16*SH_P + 8*q4];
                f16x8 hf1 = *(const f16x8*)&sHT[pp][i16*SH_P + 8*q4 + 32];
                f32x4 vw = *(const f32x4*)&sZI[pp][i16*SZ_P + 16 + 4*w];  // v[4w..4w+3]
                float pw[4] = {0.f, 0.f, 0.f, 0.f};
                #pragma unroll
                for (int t = 0; t < 4; ++t) {
                    f32x4 ac = {0.f, 0.f, 0.f, 0.f};
                    ac = __builtin_amdgcn_mfma_f32_16x16x32_f16(w2a[t][0], hf0, ac, 0, 0, 0);
                    ac = __builtin_amdgcn_mfma_f32_16x16x32_f16(w2a[t][1], hf1, ac, 0, 0, 0);
                    float a0 = ac[0] + b2v[t][0], a1 = ac[1] + b2v[t][1];
                    float a2 = ac[2] + b2v[t][2], a3 = ac[3] + b2v[t][3];
                    float vv = vw[t];
                    pw[0] += vv * a0; pw[1] += vv * a1;
                    pw[2] += vv * a2; pw[3] += vv * a3;
                    u16x4 av;
                    av.v2[0] = pk2(a0, a1);
                    av.v2[1] = pk2(a2, a3);
                    *(f16x4*)&sAG[pp][i16*SAG_P + 24*(4*w + t) + 4*q4] = av.v4;
                }
                f32x4 pwv = {pw[0], pw[1], pw[2], pw[3]};
                *(f32x4*)&sWp[pp][(w*16 + i16)*SWP_C + 4*q4] = pwv;
            }
            __syncthreads();   // B2: A + w partials ready
            // ======== AAT (both sets) -> G^T over A region ========
            #pragma unroll
            for (int pp = 0; pp < NPP; ++pp)
                #pragma unroll
                for (int u0 = 0; u0 < 2; ++u0) {
                    int pt = 2*(2*w + u0) + sc;
                    f16x8 af = *(const f16x8*)&sAG[pp][pt*SAG_P + 24*i16 + 8*h2];
                    f32x16 gz = {0.0f};
                    f32x16 gacc = __builtin_amdgcn_mfma_f32_32x32x16_f16(af, af, gz, 0, 0, 0);
                    float gv[8];
                    #pragma unroll
                    for (int rr = 0; rr < 4; ++rr) {
                        int a0 = 4*h2 + rr;
                        int a1 = 8 + 4*h2 + rr;
                        gv[rr]     = gacc[rr + 8*sc]     + ((i16 == a0) ? 1.0f : 0.0f);
                        gv[4 + rr] = gacc[rr + 4 + 8*sc] + ((i16 == a1) ? 1.0f : 0.0f);
                    }
                    u16x4 g0, g1;
                    g0.v2[0] = pk2(gv[0], gv[1]); g0.v2[1] = pk2(gv[2], gv[3]);
                    g1.v2[0] = pk2(gv[4], gv[5]); g1.v2[1] = pk2(gv[6], gv[7]);
                    *(f16x4*)&sAG[pp][pt*SAG_P + 24*i16 + 4*h2]     = g0.v4;
                    *(f16x4*)&sAG[pp][pt*SAG_P + 24*i16 + 8 + 4*h2] = g1.v4;
                }
            // ======== r (both sets): lane point i16, n=16w+4q4+reg ========
            #pragma unroll
            for (int pp = 0; pp < NPP; ++pp) {
                float wv[8];
                {
                    f32x4 s0 = *(const f32x4*)&sWp[pp][(0*16 + i16)*SWP_C + 8*sc];
                    f32x4 s1 = *(const f32x4*)&sWp[pp][(1*16 + i16)*SWP_C + 8*sc];
                    f32x4 s2 = *(const f32x4*)&sWp[pp][(2*16 + i16)*SWP_C + 8*sc];
                    f32x4 s3 = *(const f32x4*)&sWp[pp][(3*16 + i16)*SWP_C + 8*sc];
                    f32x4 t0 = *(const f32x4*)&sWp[pp][(0*16 + i16)*SWP_C + 8*sc + 4];
                    f32x4 t1 = *(const f32x4*)&sWp[pp][(1*16 + i16)*SWP_C + 8*sc + 4];
                    f32x4 t2 = *(const f32x4*)&sWp[pp][(2*16 + i16)*SWP_C + 8*sc + 4];
                    f32x4 t3 = *(const f32x4*)&sWp[pp][(3*16 + i16)*SWP_C + 8*sc + 4];
                    #pragma unroll
                    for (int j = 0; j < 4; ++j) {
                        wv[j]     = s0[j] + s1[j] + s2[j] + s3[j];
                        wv[4 + j] = t0[j] + t1[j] + t2[j] + t3[j];
                    }
                }
                float vr[16];
                {
                    #pragma unroll
                    for (int m = 0; m < 4; ++m) {
                        f32x4 v4 = *(const f32x4*)&sZI[pp][i16*SZ_P + 16 + 4*m];
                        #pragma unroll
                        for (int j = 0; j < 4; ++j) vr[4*m + j] = v4[j];
                    }
                }
                f16x2 wfp[4];
                #pragma unroll
                for (int jp = 0; jp < 4; ++jp) wfp[jp] = pk2(wv[2*jp], wv[2*jp + 1]);
                f32x4 racc = {0.f, 0.f, 0.f, 0.f};
                #pragma unroll
                for (int ch = 0; ch < 8; ++ch) {
                    f16 vvh = (f16)vr[2*ch + (q4 >> 1)];
                    f16x2 vv2; vv2.x = vvh; vv2.y = vvh;
                    u16x8 uf;
                    #pragma unroll
                    for (int jp = 0; jp < 4; ++jp) uf.v2[jp] = vv2 * wfp[jp];
                    racc = __builtin_amdgcn_mfma_f32_16x16x32_f16(w2r[ch], uf.v8, racc, 0, 0, 0);
                }
                u16x4 tv4;
                tv4.v2[0] = pk2(dreg[pp][0]*racc[0], dreg[pp][1]*racc[1]);
                tv4.v2[1] = pk2(dreg[pp][2]*racc[2], dreg[pp][3]*racc[3]);
                *(f16x4*)&sHT[pp][i16*SH_P + 16*w + 4*q4] = tv4.v4;   // t over h
            }
            __syncthreads();   // B3: t ready (G/aug wave-private from here)
            // ======== q (both sets, per wave own 4 points) ========
            #pragma unroll
            for (int pp = 0; pp < NPP; ++pp) {
                int ptq = 4*w + (i16 & 3);
                f16x8 tb0 = *(const f16x8*)&sHT[pp][ptq*SH_P + 8*q4];
                f16x8 tb1 = *(const f16x8*)&sHT[pp][ptq*SH_P + 8*q4 + 32];
                f32x4 qa = {0.f, 0.f, 0.f, 0.f};
                qa = __builtin_amdgcn_mfma_f32_16x16x32_f16(w1q[0], tb0, qa, 0, 0, 0);
                qa = __builtin_amdgcn_mfma_f32_16x16x32_f16(w1q[1], tb1, qa, 0, 0, 0);
                if (i16 < 4) {
                    #pragma unroll
                    for (int reg = 0; reg < 4; ++reg)
                        sAG[pp][(4*w + i16)*SAG_P + 24*(4*q4 + reg) + 16] = (f16)qa[reg];
                }
            }
            // ======== solve (both sets interleaved); point 4w+q4, row i16 ====
            {
                const int psl = 4*w + q4;
                float R0[17], R1[17];
                #pragma unroll
                for (int pp = 0; pp < NPP; ++pp) {
                    float (&R)[17] = pp ? R1 : R0;
                    const f16* rp = &sAG[pp][psl*SAG_P + 24*i16];
                    f16x8 ra = *(const f16x8*)&rp[0];
                    f16x8 rb = *(const f16x8*)&rp[8];
                    #pragma unroll
                    for (int j = 0; j < 8; ++j) { R[j] = (float)ra[j]; R[8+j] = (float)rb[j]; }
                    R[16] = (float)rp[16];
                }
                float inv0 = 1.0f, inv1 = 1.0f;
                fe_all2<0>(R0, R1, i16, inv0, inv1);
                sKV[0][psl*SW_P + i16] = R0[16] * inv0;
                sKV[1][psl*SW_P + i16] = R1[16] * inv1;
            }
            // (no barrier: combine reads only this wave's points; DS in-order)
            // ======== RK4 combine (both sets) ========
            #pragma unroll
            for (int pp = 0; pp < NPP; ++pp) {
                f32x2 kk;
                if (g16 < 8) kk = *(const f32x2*)&sZI[pp][p_cmb*SZ_P + 16 + 2*g16];
                else         kk = *(const f32x2*)&sKV[pp][p_cmb*SW_P + 2*(g16 - 8)];
                if (s == 0) ar[pp] = kk;
                else {
                    float wgt = (s == 3) ? 1.0f : 2.0f;
                    ar[pp].x += wgt * kk.x; ar[pp].y += wgt * kk.y;
                }
                f32x2 zi;
                if (s < 3) {
                    float alpha = (s < 2) ? (0.5f * dt) : dt;
                    zi.x = zc[pp].x + alpha * kk.x; zi.y = zc[pp].y + alpha * kk.y;
                } else {
                    float c6 = dt / 6.0f;
                    zc[pp].x += c6 * ar[pp].x; zc[pp].y += c6 * ar[pp].y;
                    zi = zc[pp];
                }
                *(f32x2*)&sZI[pp][p_cmb*SZ_P + 2*g16] = zi;
            }
            __syncthreads();   // B4: zI ready for next eval
        }
    }
    #pragma unroll
    for (int pp = 0; pp < NPP; ++pp) {
        int pg = pb + 16*pp + p_cmb;
        if (pg < B)
            *(f32x2*)&outg[pg*32 + 2*g16] = zc[pp];
    }
}

extern "C" void kernel_launch(void* const* d_in, const int* in_sizes, int n_in,
                              void* d_out, int out_size, void* d_ws, size_t ws_size,
                              hipStream_t stream) {
    (void)n_in; (void)d_ws; (void)ws_size; (void)out_size;
    const float* z  = (const float*)d_in[0];
    const float* t  = (const float*)d_in[1];
    const float* W1 = (const float*)d_in[2];
    const float* b1 = (const float*)d_in[3];
    const float* W2 = (const float*)d_in[4];
    const float* b2 = (const float*)d_in[5];
    const int*   ns = (const int*)d_in[6];
    float* out = (float*)d_out;
    const int B = in_sizes[0] / 32;
    int grid = (B + 31) / 32;
    hipLaunchKernelGGL(geo_kernel, dim3(grid), dim3(256), 0, stream,
                       z, t, W1, b1, W2, b2, ns, out, B);
}